// Round 4
// baseline (309.105 us; speedup 1.0000x reference)
//
#include <hip/hip_runtime.h>
#include <cstdint>
#include <cstddef>

constexpr int BTOT = 8192, N = 512, H = 256, K = 8;

typedef __attribute__((ext_vector_type(8))) short short8v;
typedef __attribute__((ext_vector_type(4))) float f32x4;

__device__ __forceinline__ float bf2f(unsigned short u) {
    return __uint_as_float(((uint32_t)u) << 16);
}
__device__ __forceinline__ unsigned short f2bf(float f) {
    uint32_t u = __float_as_uint(f);
    uint32_t r = (u + 0x7FFFu + ((u >> 16) & 1u)) >> 16;
    return (unsigned short)r;
}

// async global->LDS, 16B per lane; LDS dest is wave-uniform base + lane*16
typedef __attribute__((address_space(3))) unsigned int lds_uint;
typedef __attribute__((address_space(1))) const unsigned int glob_uint;
__device__ __forceinline__ void async16(const unsigned short* g, unsigned short* l) {
    __builtin_amdgcn_global_load_lds((glob_uint*)g, (lds_uint*)l, 16, 0, 0);
}

// ============ grouped 128x128 bf16 MFMA GEMM with fused epilogues ============
// C[M x Nn] = A[M x Ka] @ Bt^T, A/Bt row-major bf16. blockIdx.z picks the group.
struct GArg {
    const unsigned short* A;
    const unsigned short* Bt;
    const float* bias;            // EPI_FWD
    const unsigned short* dmul;   // EPI_BWD2: dsilu(a1) bf16
    const float* alpha;           // EPI_NEGV
    const unsigned short* vsub;   // EPI_NEGV: v-matrix (B x K*N bf16)
    unsigned short* ob;           // bf16 out (h / t2 / v)
    unsigned short* ob2;          // EPI_FWD: dsilu out
    float* of;                    // EPI_NEG/NEGV fp32 out
    float* qout;                  // EPI_BF: fused q atomics (v0 side)
    const unsigned short* xq;     // EPI_BF: x1 base (ld 1024)
    float* sout;                  // EPI_FWD: fused gate-logit atomics
    const float* w3s;             // EPI_FWD: gt_w3 [H][K] fp32
    int lda, ldbt, Ka, lddm, ldob, ldof;
};

enum { EPI_BF = 0, EPI_FWD = 1, EPI_BWD2 = 2, EPI_NEG = 3, EPI_NEGV = 4 };

template<int EPI>
__global__ __launch_bounds__(256) void gemm_g(GArg ga0, GArg ga1, GArg ga2)
{
    const int z = blockIdx.z;
    const GArg g = (z == 0) ? ga0 : (z == 1) ? ga1 : ga2;

    // double-buffered linear LDS: 2 x 128 rows x 32 bf16 per operand (32KB)
    __shared__ __attribute__((aligned(16))) unsigned short As[2][128 * 32];
    __shared__ __attribute__((aligned(16))) unsigned short Bs[2][128 * 32];
    const int tid = threadIdx.x;
    const int lane = tid & 63, wave = tid >> 6;

    // XCD-aware x swizzle (bijective when gridDim.x % 8 == 0)
    int bx = blockIdx.x;
    if ((gridDim.x & 7) == 0) bx = (bx & 7) * (gridDim.x >> 3) + (bx >> 3);

    const int m0 = blockIdx.y * 128, n0 = bx * 128;
    const int wr = (wave >> 1) * 64, wc = (wave & 1) * 64;
    const int rr = lane & 15;
    const int kb = ((lane >> 4) ^ (lane & 3)) << 3;      // swizzled read slot

    // staging: thread t covers (row r0, slot t&3) and (row r0+64, slot t&3)
    const int r0 = tid >> 2;
    const int ko0 = (((tid & 3) ^ (r0 & 3)) << 3);       // pre-swizzled source
    const unsigned short* gA0 = g.A + (size_t)(m0 + r0) * g.lda + ko0;
    const unsigned short* gA1 = g.A + (size_t)(m0 + r0 + 64) * g.lda + ko0;
    const unsigned short* gB0 = g.Bt + (size_t)(n0 + r0) * g.ldbt + ko0;
    const unsigned short* gB1 = g.Bt + (size_t)(n0 + r0 + 64) * g.ldbt + ko0;

    f32x4 acc[4][4];
    #pragma unroll
    for (int i = 0; i < 4; ++i)
        #pragma unroll
        for (int j = 0; j < 4; ++j) acc[i][j] = (f32x4){0.f, 0.f, 0.f, 0.f};

    const int nt = g.Ka >> 5;

    // prologue: stage tile 0 into buffer 0
    async16(gA0, &As[0][tid * 8]);
    async16(gA1, &As[0][(tid + 256) * 8]);
    async16(gB0, &Bs[0][tid * 8]);
    async16(gB1, &Bs[0][(tid + 256) * 8]);
    asm volatile("s_waitcnt vmcnt(0)" ::: "memory");
    __builtin_amdgcn_s_barrier();

    int cur = 0;
    for (int t = 0; t < nt; ++t) {
        if (t + 1 < nt) {                 // stage next tile into other buffer
            const int k0 = (t + 1) << 5;
            async16(gA0 + k0, &As[cur ^ 1][tid * 8]);
            async16(gA1 + k0, &As[cur ^ 1][(tid + 256) * 8]);
            async16(gB0 + k0, &Bs[cur ^ 1][tid * 8]);
            async16(gB1 + k0, &Bs[cur ^ 1][(tid + 256) * 8]);
        }
        short8v af[4], bfr[4];
        #pragma unroll
        for (int i = 0; i < 4; ++i)
            af[i] = *(const short8v*)(&As[cur][(wr + i * 16 + rr) * 32 + kb]);
        #pragma unroll
        for (int j = 0; j < 4; ++j)
            bfr[j] = *(const short8v*)(&Bs[cur][(wc + j * 16 + rr) * 32 + kb]);
        #pragma unroll
        for (int i = 0; i < 4; ++i)
            #pragma unroll
            for (int j = 0; j < 4; ++j)
                acc[i][j] = __builtin_amdgcn_mfma_f32_16x16x32_bf16(af[i], bfr[j], acc[i][j], 0, 0, 0);
        asm volatile("s_waitcnt vmcnt(0)" ::: "memory");  // next tile landed
        __builtin_amdgcn_s_barrier();
        cur ^= 1;
    }

    const int orow = (lane >> 4) * 4;
    #pragma unroll
    for (int i = 0; i < 4; ++i) {
        #pragma unroll
        for (int e = 0; e < 4; ++e) {
            const int row = m0 + wr + i * 16 + orow + e;
            if constexpr (EPI == EPI_NEGV) {
                float al[K];
                #pragma unroll
                for (int kk = 0; kk < K; ++kk) al[kk] = g.alpha[(size_t)row * K + kk];
                #pragma unroll
                for (int j = 0; j < 4; ++j) {
                    const int col = n0 + wc + rr + j * 16;
                    const unsigned short* vp = g.vsub + (size_t)row * (K * N) + col;
                    float sub = 0.f;
                    #pragma unroll
                    for (int kk = 0; kk < K; ++kk) sub += al[kk] * bf2f(vp[(size_t)kk * N]);
                    g.of[(size_t)row * g.ldof + col] = -acc[i][j][e] - sub;
                }
            } else if constexpr (EPI == EPI_FWD) {
                float sq[K];
                const bool do_s = (g.sout != nullptr);
                #pragma unroll
                for (int kk = 0; kk < K; ++kk) sq[kk] = 0.f;
                #pragma unroll
                for (int j = 0; j < 4; ++j) {
                    const int col = n0 + wc + rr + j * 16;
                    float p = acc[i][j][e] + g.bias[col];
                    float s = 1.f / (1.f + expf(-p));
                    if (g.ob) g.ob[(size_t)row * g.ldob + col] = f2bf(p * s);
                    g.ob2[(size_t)row * g.ldob + col] = f2bf(s * (1.f + p * (1.f - s)));
                    if (do_s) {
                        float sl = p * s;
                        float4 wa = *(const float4*)(g.w3s + (size_t)col * K);
                        float4 wb = *(const float4*)(g.w3s + (size_t)col * K + 4);
                        sq[0] += sl * wa.x; sq[1] += sl * wa.y;
                        sq[2] += sl * wa.z; sq[3] += sl * wa.w;
                        sq[4] += sl * wb.x; sq[5] += sl * wb.y;
                        sq[6] += sl * wb.z; sq[7] += sl * wb.w;
                    }
                }
                if (do_s) {
                    #pragma unroll
                    for (int m = 1; m < 16; m <<= 1)
                        #pragma unroll
                        for (int kk = 0; kk < K; ++kk) sq[kk] += __shfl_xor(sq[kk], m, 64);
                    if ((lane & 15) == 0)
                        #pragma unroll
                        for (int kk = 0; kk < K; ++kk)
                            atomicAdd(g.sout + (size_t)row * K + kk, sq[kk]);
                }
            } else {
                #pragma unroll
                for (int j = 0; j < 4; ++j) {
                    const int col = n0 + wc + rr + j * 16;
                    float v = acc[i][j][e];
                    if constexpr (EPI == EPI_BF) {
                        g.ob[(size_t)row * g.ldob + col] = f2bf(v);
                    } else if constexpr (EPI == EPI_BWD2) {
                        float t = v * bf2f(g.dmul[(size_t)row * g.lddm + col]);
                        g.ob[(size_t)row * g.ldob + col] = f2bf(t);
                    } else if constexpr (EPI == EPI_NEG) {
                        g.of[(size_t)row * g.ldof + col] -= v;
                    }
                }
            }
            if constexpr (EPI == EPI_BF) {
                if (g.qout) {   // fused q: this block's cols are i-range of kq
                    const int kq = n0 >> 9, i0 = n0 & 511;
                    float sqv = 0.f;
                    #pragma unroll
                    for (int j = 0; j < 4; ++j) {
                        const int ic = i0 + wc + rr + j * 16;
                        sqv += acc[i][j][e] * bf2f(g.xq[(size_t)row * 1024 + ic]);
                    }
                    #pragma unroll
                    for (int m = 1; m < 16; m <<= 1) sqv += __shfl_xor(sqv, m, 64);
                    if ((lane & 15) == 0)
                        atomicAdd(g.qout + (size_t)row * K + kq, sqv);
                }
            }
        }
    }
}

// ---------------- prep kernels ----------------
__global__ __launch_bounds__(256) void k_cvt_z(const float* __restrict__ z,
                                               unsigned short* __restrict__ o) {
    int g = (blockIdx.x * 256 + threadIdx.x) * 4;
    float4 v = *(const float4*)(z + g);
    ushort4 u;
    u.x = f2bf(v.x); u.y = f2bf(v.y); u.z = f2bf(v.z); u.w = f2bf(v.w);
    *(ushort4*)(o + g) = u;
}

// Wbf[k][i][j] = bf16(W[k][i][j]);  WTbf[k][j][i] = bf16(W[k][i][j])
__global__ __launch_bounds__(256) void k_transpose_w(const float* __restrict__ W,
    unsigned short* __restrict__ Wbf, unsigned short* __restrict__ WTbf)
{
    __shared__ float t[32][33];
    int k = blockIdx.z;
    int i0 = blockIdx.y * 32, j0 = blockIdx.x * 32;
    int tj = threadIdx.x & 31, ti = threadIdx.x >> 5;
    const float* Wk = W + (size_t)k * N * N;
    #pragma unroll
    for (int r = 0; r < 32; r += 8) {
        float v = Wk[(size_t)(i0 + ti + r) * N + j0 + tj];
        t[ti + r][tj] = v;
        Wbf[(size_t)k * N * N + (size_t)(i0 + ti + r) * N + j0 + tj] = f2bf(v);
    }
    __syncthreads();
    #pragma unroll
    for (int r = 0; r < 32; r += 8)
        WTbf[(size_t)k * N * N + (size_t)(j0 + ti + r) * N + i0 + tj] = f2bf(t[tj][ti + r]);
}

// table-driven weight convert (optionally transposed): one launch for all 12 jobs
struct CvtJob { const float* src; unsigned short* dst; int ls, ld, cols32, tiles, trans; };
struct CvtTable { CvtJob j[12]; };

__global__ __launch_bounds__(256) void k_cvt_w(CvtTable T)
{
    int t = blockIdx.x;
    int ji = 0;
    while (t >= T.j[ji].tiles) { t -= T.j[ji].tiles; ++ji; }
    CvtJob jb = T.j[ji];
    int i0 = (t / jb.cols32) * 32, c0 = (t % jb.cols32) * 32;
    int tc = threadIdx.x & 31, tr = threadIdx.x >> 5;
    if (!jb.trans) {
        #pragma unroll
        for (int r = 0; r < 32; r += 8)
            jb.dst[(size_t)(i0 + tr + r) * jb.ld + c0 + tc] =
                f2bf(jb.src[(size_t)(i0 + tr + r) * jb.ls + c0 + tc]);
    } else {
        __shared__ float tt[32][33];
        #pragma unroll
        for (int r = 0; r < 32; r += 8)
            tt[tr + r][tc] = jb.src[(size_t)(i0 + tr + r) * jb.ls + c0 + tc];
        __syncthreads();
        #pragma unroll
        for (int r = 0; r < 32; r += 8)
            jb.dst[(size_t)(c0 + tr + r) * jb.ld + i0 + tc] = f2bf(tt[tc][tr + r]);
    }
}

// ---------------- small fused kernels ----------------
__global__ __launch_bounds__(256) void k_d(const float* __restrict__ s,
    const float* __restrict__ b3t,
    const float* __restrict__ q, float* __restrict__ alpha,
    float* __restrict__ dd, int Bc)
{
    int b = blockIdx.x * 256 + threadIdx.x;
    if (b >= Bc) return;
    float sv[K], qv[K];
    float m = -1e30f;
    #pragma unroll
    for (int k = 0; k < K; ++k) { sv[k] = s[b * K + k] + b3t[k]; m = fmaxf(m, sv[k]); }
    float sum = 0.f;
    #pragma unroll
    for (int k = 0; k < K; ++k) { sv[k] = expf(sv[k] - m); sum += sv[k]; }
    float inv = 1.f / sum, qbar = 0.f;
    #pragma unroll
    for (int k = 0; k < K; ++k) { sv[k] *= inv; qv[k] = q[b * K + k]; qbar += sv[k] * qv[k]; }
    #pragma unroll
    for (int k = 0; k < K; ++k) {
        alpha[b * K + k] = sv[k];
        dd[b * K + k] = sv[k] * (qv[k] - qbar);
    }
}

// merged u2 for all three subnets
__global__ __launch_bounds__(256) void k_u2(
    const unsigned short* __restrict__ d2_0, const unsigned short* __restrict__ d2_1,
    const unsigned short* __restrict__ d2_t,
    const float* __restrict__ w3_0, const float* __restrict__ w3_1,
    const float* __restrict__ w3t, const float* __restrict__ dd,
    unsigned short* __restrict__ u2_0, unsigned short* __restrict__ u2_1,
    unsigned short* __restrict__ u2_t)
{
    int g = blockIdx.x * 256 + threadIdx.x;
    int h = g & (H - 1), b = g >> 8;
    u2_0[g] = f2bf(w3_0[h] * bf2f(d2_0[g]));
    u2_1[g] = f2bf(w3_1[h] * bf2f(d2_1[g]));
    float s = 0.f;
    #pragma unroll
    for (int k = 0; k < K; ++k) s += w3t[h * K + k] * dd[b * K + k];
    u2_t[g] = f2bf(s * bf2f(d2_t[g]));
}

// fallback (chunked) path: out[:, :N] -= sum_k a_k v1; out[:, N:] -= sum_k a_k v0
__global__ __launch_bounds__(256) void k_gxq2(const unsigned short* __restrict__ v0,
    const unsigned short* __restrict__ v1, const float* __restrict__ alpha,
    float* __restrict__ out)
{
    int g = blockIdx.x * 256 + threadIdx.x;
    int b = g >> 6, jb = (g & 63) << 3;
    float al[K];
    #pragma unroll
    for (int k = 0; k < K; ++k) al[k] = alpha[b * K + k];
    const unsigned short* pv0 = v0 + (size_t)b * K * N + jb;
    const unsigned short* pv1 = v1 + (size_t)b * K * N + jb;
    float s0[8] = {}, s1[8] = {};
    #pragma unroll
    for (int k = 0; k < K; ++k) {
        short8v w1 = *(const short8v*)(pv1 + (size_t)k * N);
        short8v w0 = *(const short8v*)(pv0 + (size_t)k * N);
        #pragma unroll
        for (int t = 0; t < 8; ++t) {
            s0[t] += al[k] * bf2f((unsigned short)w1[t]);
            s1[t] += al[k] * bf2f((unsigned short)w0[t]);
        }
    }
    float* o0 = out + (size_t)b * 1024 + jb;
    float* o1 = o0 + 512;
    float4 x0 = *(float4*)o0, x1 = *(float4*)(o0 + 4);
    x0.x -= s0[0]; x0.y -= s0[1]; x0.z -= s0[2]; x0.w -= s0[3];
    x1.x -= s0[4]; x1.y -= s0[5]; x1.z -= s0[6]; x1.w -= s0[7];
    *(float4*)o0 = x0; *(float4*)(o0 + 4) = x1;
    float4 y0 = *(float4*)o1, y1 = *(float4*)(o1 + 4);
    y0.x -= s1[0]; y0.y -= s1[1]; y0.z -= s1[2]; y0.w -= s1[3];
    y1.x -= s1[4]; y1.y -= s1[5]; y1.z -= s1[6]; y1.w -= s1[7];
    *(float4*)o1 = y0; *(float4*)(o1 + 4) = y1;
}

extern "C" void kernel_launch(void* const* d_in, const int* in_sizes, int n_in,
                              void* d_out, int out_size, void* d_ws, size_t ws_size,
                              hipStream_t stream) {
    const float* z     = (const float*)d_in[0];
    const float* g0_w1 = (const float*)d_in[1];  const float* g0_b1 = (const float*)d_in[2];
    const float* g0_w2 = (const float*)d_in[3];  const float* g0_b2 = (const float*)d_in[4];
    const float* g0_w3 = (const float*)d_in[5];
    const float* g1_w1 = (const float*)d_in[7];  const float* g1_b1 = (const float*)d_in[8];
    const float* g1_w2 = (const float*)d_in[9];  const float* g1_b2 = (const float*)d_in[10];
    const float* g1_w3 = (const float*)d_in[11];
    const float* gt_w1 = (const float*)d_in[13]; const float* gt_b1 = (const float*)d_in[14];
    const float* gt_w2 = (const float*)d_in[15]; const float* gt_b2 = (const float*)d_in[16];
    const float* gt_w3 = (const float*)d_in[17]; const float* gt_b3 = (const float*)d_in[18];
    const float* W     = (const float*)d_in[19];
    float* out = (float*)d_out;

    // ---- workspace layout ----
    char* wsb = (char*)d_ws;
    size_t off = 0;
    auto aus = [&](size_t n) -> unsigned short* {
        unsigned short* r = (unsigned short*)(wsb + off);
        off += ((n * 2 + 255) & ~(size_t)255);
        return r;
    };
    auto af4 = [&](size_t n) -> float* {
        float* r = (float*)(wsb + off);
        off += ((n * 4 + 255) & ~(size_t)255);
        return r;
    };

    unsigned short* Zbf  = aus((size_t)BTOT * 1024);
    unsigned short* Wbf  = aus((size_t)K * N * N);
    unsigned short* WTbf = aus((size_t)K * N * N);
    unsigned short* w1T[3], *w2T[3], *w2N[3];
    for (int i = 0; i < 3; ++i) w1T[i] = aus((size_t)H * N);
    for (int i = 0; i < 3; ++i) w2T[i] = aus((size_t)H * H);
    for (int i = 0; i < 3; ++i) w2N[i] = aus((size_t)H * H);
    unsigned short* w1N1  = aus((size_t)N * H);
    unsigned short* w1cat = aus((size_t)N * 2 * H);
    unsigned short* h1[3], *d1b[3], *d2b[3], *u2[3];
    for (int i = 0; i < 3; ++i) h1[i]  = aus((size_t)BTOT * H);
    for (int i = 0; i < 3; ++i) d1b[i] = aus((size_t)BTOT * H);
    for (int i = 0; i < 3; ++i) d2b[i] = aus((size_t)BTOT * H);
    for (int i = 0; i < 3; ++i) u2[i]  = aus((size_t)BTOT * H);
    unsigned short* t2cat = aus((size_t)BTOT * 512);
    unsigned short* t21   = aus((size_t)BTOT * H);
    float* sbuf = af4((size_t)BTOT * K);
    float* qbuf = af4((size_t)BTOT * K);
    float* abuf = af4((size_t)BTOT * K);
    float* dbuf = af4((size_t)BTOT * K);

    int Bcv = BTOT;
    while (off + 2 * (((size_t)Bcv * K * N * 2 + 255) & ~(size_t)255) > ws_size && Bcv > 128)
        Bcv >>= 1;
    unsigned short* v0 = aus((size_t)Bcv * K * N);
    unsigned short* v1 = aus((size_t)Bcv * K * N);
    const bool full = (Bcv == BTOT);

    const dim3 blk(256);

    if (!full)  // fallback path needs zeroed out for RMW accumulation
        hipMemsetAsync(d_out, 0, (size_t)out_size * sizeof(float), stream);
    // fused q/s epilogues accumulate atomically -> zero-init
    hipMemsetAsync(qbuf, 0, (size_t)BTOT * K * sizeof(float), stream);
    hipMemsetAsync(sbuf, 0, (size_t)BTOT * K * sizeof(float), stream);

    // ---- prep: bf16 copies ----
    k_cvt_z<<<BTOT * 1024 / (256 * 4), blk, 0, stream>>>(z, Zbf);
    k_transpose_w<<<dim3(N / 32, N / 32, K), blk, 0, stream>>>(W, Wbf, WTbf);

    CvtTable T;
    int nj = 0, tot = 0;
    auto addjob = [&](const float* src, int ls, unsigned short* dst, int ld,
                      int rows, int cols, int trans) {
        CvtJob jb; jb.src = src; jb.dst = dst; jb.ls = ls; jb.ld = ld;
        jb.cols32 = cols / 32; jb.tiles = (rows / 32) * (cols / 32); jb.trans = trans;
        T.j[nj++] = jb; tot += jb.tiles;
    };
    addjob(g0_w1, H, w1T[0], N, N, H, 1);
    addjob(g1_w1, H, w1T[1], N, N, H, 1);
    addjob(gt_w1, H, w1T[2], N, N, H, 1);
    addjob(g0_w2, H, w2T[0], H, H, H, 1);
    addjob(g1_w2, H, w2T[1], H, H, H, 1);
    addjob(gt_w2, H, w2T[2], H, H, H, 1);
    addjob(g0_w2, H, w2N[0], H, H, H, 0);
    addjob(g1_w2, H, w2N[1], H, H, H, 0);
    addjob(gt_w2, H, w2N[2], H, H, H, 0);
    addjob(g1_w1, H, w1N1, H, N, H, 0);
    addjob(g0_w1, H, w1cat, 2 * H, N, H, 0);
    addjob(gt_w1, H, w1cat + H, 2 * H, N, H, 0);
    k_cvt_w<<<tot, blk, 0, stream>>>(T);

    auto mk = [](const unsigned short* A, int lda, const unsigned short* Bt, int ldbt, int Ka) {
        GArg g; g.A = A; g.Bt = Bt; g.bias = nullptr; g.dmul = nullptr;
        g.alpha = nullptr; g.vsub = nullptr;
        g.ob = nullptr; g.ob2 = nullptr; g.of = nullptr;
        g.qout = nullptr; g.xq = nullptr; g.sout = nullptr; g.w3s = nullptr;
        g.lda = lda; g.ldbt = ldbt; g.Ka = Ka; g.lddm = 0; g.ldob = 0; g.ldof = 0;
        return g;
    };

    // ---- forward L1 (grouped) -> h1 (silu) + d1 (dsilu) ----
    {
        const float* bs[3] = {g0_b1, g1_b1, gt_b1};
        GArg a[3];
        for (int i = 0; i < 3; ++i) {
            a[i] = mk(Zbf + (i == 1 ? 512 : 0), 1024, w1T[i], N, N);
            a[i].bias = bs[i]; a[i].ob = h1[i]; a[i].ob2 = d1b[i]; a[i].ldob = H;
        }
        gemm_g<EPI_FWD><<<dim3(H / 128, BTOT / 128, 3), blk, 0, stream>>>(a[0], a[1], a[2]);
    }
    // ---- forward L2 (grouped) -> d2 (dsilu); gate logits fused for z==2 ----
    {
        const float* bs[3] = {g0_b2, g1_b2, gt_b2};
        GArg a[3];
        for (int i = 0; i < 3; ++i) {
            a[i] = mk(h1[i], H, w2T[i], H, H);
            a[i].bias = bs[i]; a[i].ob = nullptr;
            a[i].ob2 = d2b[i]; a[i].ldob = H;
        }
        a[2].sout = sbuf; a[2].w3s = gt_w3;
        gemm_g<EPI_FWD><<<dim3(H / 128, BTOT / 128, 3), blk, 0, stream>>>(a[0], a[1], a[2]);
    }

    // ---- bilinear path (q fused into v0 epilogue) ----
    for (int cb = 0; cb < BTOT; cb += Bcv) {
        GArg a[2];
        a[0] = mk(Zbf + (size_t)cb * 1024, 1024, Wbf, N, N);
        a[0].ob = v0; a[0].ldob = K * N;
        a[0].qout = qbuf + (size_t)cb * K;
        a[0].xq = Zbf + (size_t)cb * 1024 + 512;
        a[1] = mk(Zbf + (size_t)cb * 1024 + 512, 1024, WTbf, N, N);
        a[1].ob = v1; a[1].ldob = K * N;
        gemm_g<EPI_BF><<<dim3(K * N / 128, Bcv / 128, 2), blk, 0, stream>>>(a[0], a[1], a[1]);

        k_d<<<(Bcv + 255) / 256, blk, 0, stream>>>(sbuf + (size_t)cb * K, gt_b3,
                                                   qbuf + (size_t)cb * K,
                                                   abuf + (size_t)cb * K, dbuf + (size_t)cb * K, Bcv);
        if (!full)
            k_gxq2<<<Bcv * 64 / 256, blk, 0, stream>>>(v0, v1, abuf + (size_t)cb * K,
                                                       out + (size_t)cb * 1024);
    }

    // ---- backward: u2 = dL/da2 (all three subnets, one launch) ----
    k_u2<<<BTOT * H / 256, blk, 0, stream>>>(d2b[0], d2b[1], d2b[2],
                                             g0_w3, g1_w3, gt_w3, dbuf,
                                             u2[0], u2[1], u2[2]);

    // ---- backward L2 (grouped): t2 = (u2 @ w2^T) * d1 -> bf16 ----
    {
        GArg a[3];
        a[0] = mk(u2[0], H, w2N[0], H, H);
        a[0].dmul = d1b[0]; a[0].lddm = H; a[0].ob = t2cat;     a[0].ldob = 512;
        a[1] = mk(u2[1], H, w2N[1], H, H);
        a[1].dmul = d1b[1]; a[1].lddm = H; a[1].ob = t21;       a[1].ldob = H;
        a[2] = mk(u2[2], H, w2N[2], H, H);
        a[2].dmul = d1b[2]; a[2].lddm = H; a[2].ob = t2cat + H; a[2].ldob = 512;
        gemm_g<EPI_BWD2><<<dim3(H / 128, BTOT / 128, 3), blk, 0, stream>>>(a[0], a[1], a[2]);
    }
    // ---- backward L1 (grouped): g0+gt concatenated (Ka=512), g1 ----
    // full path: epilogue fuses  out = -acc - sum_k alpha_k * v  (kills k_gxq2)
    {
        GArg a[2];
        a[0] = mk(t2cat, 512, w1cat, 2 * H, 512);
        a[0].of = out;       a[0].ldof = 1024;
        a[1] = mk(t21, H, w1N1, H, H);
        a[1].of = out + 512; a[1].ldof = 1024;
        if (full) {
            a[0].alpha = abuf; a[0].vsub = v1;
            a[1].alpha = abuf; a[1].vsub = v0;
            gemm_g<EPI_NEGV><<<dim3(N / 128, BTOT / 128, 2), blk, 0, stream>>>(a[0], a[1], a[1]);
        } else {
            gemm_g<EPI_NEG><<<dim3(N / 128, BTOT / 128, 2), blk, 0, stream>>>(a[0], a[1], a[1]);
        }
    }
}

// Round 5
// 246.025 us; speedup vs baseline: 1.2564x; 1.2564x over previous
//
#include <hip/hip_runtime.h>
#include <cstdint>
#include <cstddef>

constexpr int BTOT = 8192, N = 512, H = 256, K = 8;

typedef __attribute__((ext_vector_type(8))) short short8v;
typedef __attribute__((ext_vector_type(4))) float f32x4;

__device__ __forceinline__ float bf2f(unsigned short u) {
    return __uint_as_float(((uint32_t)u) << 16);
}
__device__ __forceinline__ unsigned short f2bf(float f) {
    uint32_t u = __float_as_uint(f);
    uint32_t r = (u + 0x7FFFu + ((u >> 16) & 1u)) >> 16;
    return (unsigned short)r;
}

// async global->LDS, 16B per lane; LDS dest is wave-uniform base + lane*16
typedef __attribute__((address_space(3))) unsigned int lds_uint;
typedef __attribute__((address_space(1))) const unsigned int glob_uint;
__device__ __forceinline__ void async16(const unsigned short* g, unsigned short* l) {
    __builtin_amdgcn_global_load_lds((glob_uint*)g, (lds_uint*)l, 16, 0, 0);
}

// ============ grouped 128x128 bf16 MFMA GEMM with fused epilogues ============
// C[M x Nn] = A[M x Ka] @ Bt^T, A/Bt row-major bf16. blockIdx.z picks the group.
// 3-stage pipeline, counted vmcnt(4): wait on loads issued 2 K-steps earlier.
struct GArg {
    const unsigned short* A;
    const unsigned short* Bt;
    const float* bias;            // EPI_FWD
    const unsigned short* dmul;   // EPI_BWD2: dsilu(a1) bf16
    const float* alpha;           // EPI_NEGV
    const unsigned short* vsub;   // EPI_NEGV: v-matrix (B x K*N bf16)
    unsigned short* ob;           // bf16 out (h / t2 / v)
    unsigned short* ob2;          // EPI_FWD: dsilu out
    float* of;                    // EPI_NEG/NEGV fp32 out
    int lda, ldbt, Ka, lddm, ldob, ldof;
};

enum { EPI_BF = 0, EPI_FWD = 1, EPI_BWD2 = 2, EPI_NEG = 3, EPI_NEGV = 4 };

template<int EPI>
__global__ __launch_bounds__(256) void gemm_g(GArg ga0, GArg ga1, GArg ga2)
{
    const int z = blockIdx.z;
    const GArg g = (z == 0) ? ga0 : (z == 1) ? ga1 : ga2;

    // triple-buffered linear LDS: 3 x 128 rows x 32 bf16 per operand (48KB)
    __shared__ __attribute__((aligned(16))) unsigned short As[3][128 * 32];
    __shared__ __attribute__((aligned(16))) unsigned short Bs[3][128 * 32];
    const int tid = threadIdx.x;
    const int lane = tid & 63, wave = tid >> 6;
    const int m0 = blockIdx.y * 128, n0 = blockIdx.x * 128;
    const int wr = (wave >> 1) * 64, wc = (wave & 1) * 64;
    const int rr = lane & 15;
    const int kb = ((lane >> 4) ^ (lane & 3)) << 3;      // swizzled read slot

    // staging: thread t covers (row r0, slot t&3) and (row r0+64, slot t&3)
    const int r0 = tid >> 2;
    const int ko0 = (((tid & 3) ^ (r0 & 3)) << 3);       // pre-swizzled source
    const unsigned short* gA0 = g.A + (size_t)(m0 + r0) * g.lda + ko0;
    const unsigned short* gA1 = g.A + (size_t)(m0 + r0 + 64) * g.lda + ko0;
    const unsigned short* gB0 = g.Bt + (size_t)(n0 + r0) * g.ldbt + ko0;
    const unsigned short* gB1 = g.Bt + (size_t)(n0 + r0 + 64) * g.ldbt + ko0;

    auto stage = [&](int t, int buf) {
        const int k0 = t << 5;
        async16(gA0 + k0, &As[buf][tid * 8]);
        async16(gA1 + k0, &As[buf][(tid + 256) * 8]);
        async16(gB0 + k0, &Bs[buf][tid * 8]);
        async16(gB1 + k0, &Bs[buf][(tid + 256) * 8]);
    };

    f32x4 acc[4][4];
    #pragma unroll
    for (int i = 0; i < 4; ++i)
        #pragma unroll
        for (int j = 0; j < 4; ++j) acc[i][j] = (f32x4){0.f, 0.f, 0.f, 0.f};

    const int nt = g.Ka >> 5;

    // prologue: stage tiles 0 and 1
    stage(0, 0);
    if (nt > 1) stage(1, 1);

    int buf = 0;
    for (int t = 0; t < nt; ++t) {
        // outstanding: <=8 vmem ops (tiles t, t+1); vmcnt(4) -> tile t landed.
        if (t + 1 < nt) { asm volatile("s_waitcnt vmcnt(4)" ::: "memory"); }
        else            { asm volatile("s_waitcnt vmcnt(0)" ::: "memory"); }
        __builtin_amdgcn_s_barrier();
        if (t + 2 < nt) {
            int b2 = buf + 2; if (b2 >= 3) b2 -= 3;
            stage(t + 2, b2);
        }
        short8v af[4], bfr[4];
        #pragma unroll
        for (int i = 0; i < 4; ++i)
            af[i] = *(const short8v*)(&As[buf][(wr + i * 16 + rr) * 32 + kb]);
        #pragma unroll
        for (int j = 0; j < 4; ++j)
            bfr[j] = *(const short8v*)(&Bs[buf][(wc + j * 16 + rr) * 32 + kb]);
        #pragma unroll
        for (int i = 0; i < 4; ++i)
            #pragma unroll
            for (int j = 0; j < 4; ++j)
                acc[i][j] = __builtin_amdgcn_mfma_f32_16x16x32_bf16(af[i], bfr[j], acc[i][j], 0, 0, 0);
        if (++buf == 3) buf = 0;
    }

    const int orow = (lane >> 4) * 4;
    #pragma unroll
    for (int i = 0; i < 4; ++i) {
        #pragma unroll
        for (int e = 0; e < 4; ++e) {
            const int row = m0 + wr + i * 16 + orow + e;
            if constexpr (EPI == EPI_NEGV) {
                float al[K];
                #pragma unroll
                for (int kk = 0; kk < K; ++kk) al[kk] = g.alpha[(size_t)row * K + kk];
                #pragma unroll
                for (int j = 0; j < 4; ++j) {
                    const int col = n0 + wc + rr + j * 16;
                    const unsigned short* vp = g.vsub + (size_t)row * (K * N) + col;
                    float sub = 0.f;
                    #pragma unroll
                    for (int kk = 0; kk < K; ++kk) sub += al[kk] * bf2f(vp[(size_t)kk * N]);
                    g.of[(size_t)row * g.ldof + col] = -acc[i][j][e] - sub;
                }
            } else {
                #pragma unroll
                for (int j = 0; j < 4; ++j) {
                    const int col = n0 + wc + rr + j * 16;
                    float v = acc[i][j][e];
                    if constexpr (EPI == EPI_BF) {
                        g.ob[(size_t)row * g.ldob + col] = f2bf(v);
                    } else if constexpr (EPI == EPI_FWD) {
                        float p = v + g.bias[col];
                        float s = 1.f / (1.f + expf(-p));
                        if (g.ob) g.ob[(size_t)row * g.ldob + col] = f2bf(p * s);
                        g.ob2[(size_t)row * g.ldob + col] = f2bf(s * (1.f + p * (1.f - s)));
                    } else if constexpr (EPI == EPI_BWD2) {
                        float t = v * bf2f(g.dmul[(size_t)row * g.lddm + col]);
                        g.ob[(size_t)row * g.ldob + col] = f2bf(t);
                    } else if constexpr (EPI == EPI_NEG) {
                        g.of[(size_t)row * g.ldof + col] -= v;
                    }
                }
            }
        }
    }
}

// ---------------- prep kernels ----------------
__global__ __launch_bounds__(256) void k_cvt_z(const float* __restrict__ z,
                                               unsigned short* __restrict__ o) {
    int g = (blockIdx.x * 256 + threadIdx.x) * 4;
    float4 v = *(const float4*)(z + g);
    ushort4 u;
    u.x = f2bf(v.x); u.y = f2bf(v.y); u.z = f2bf(v.z); u.w = f2bf(v.w);
    *(ushort4*)(o + g) = u;
}

// Wbf[k][i][j] = bf16(W[k][i][j]);  WTbf[k][j][i] = bf16(W[k][i][j])
__global__ __launch_bounds__(256) void k_transpose_w(const float* __restrict__ W,
    unsigned short* __restrict__ Wbf, unsigned short* __restrict__ WTbf)
{
    __shared__ float t[32][33];
    int k = blockIdx.z;
    int i0 = blockIdx.y * 32, j0 = blockIdx.x * 32;
    int tj = threadIdx.x & 31, ti = threadIdx.x >> 5;
    const float* Wk = W + (size_t)k * N * N;
    #pragma unroll
    for (int r = 0; r < 32; r += 8) {
        float v = Wk[(size_t)(i0 + ti + r) * N + j0 + tj];
        t[ti + r][tj] = v;
        Wbf[(size_t)k * N * N + (size_t)(i0 + ti + r) * N + j0 + tj] = f2bf(v);
    }
    __syncthreads();
    #pragma unroll
    for (int r = 0; r < 32; r += 8)
        WTbf[(size_t)k * N * N + (size_t)(j0 + ti + r) * N + i0 + tj] = f2bf(t[tj][ti + r]);
}

// table-driven weight convert (optionally transposed): one launch for all 12 jobs
struct CvtJob { const float* src; unsigned short* dst; int ls, ld, cols32, tiles, trans; };
struct CvtTable { CvtJob j[12]; };

__global__ __launch_bounds__(256) void k_cvt_w(CvtTable T)
{
    int t = blockIdx.x;
    int ji = 0;
    while (t >= T.j[ji].tiles) { t -= T.j[ji].tiles; ++ji; }
    CvtJob jb = T.j[ji];
    int i0 = (t / jb.cols32) * 32, c0 = (t % jb.cols32) * 32;
    int tc = threadIdx.x & 31, tr = threadIdx.x >> 5;
    if (!jb.trans) {
        #pragma unroll
        for (int r = 0; r < 32; r += 8)
            jb.dst[(size_t)(i0 + tr + r) * jb.ld + c0 + tc] =
                f2bf(jb.src[(size_t)(i0 + tr + r) * jb.ls + c0 + tc]);
    } else {
        __shared__ float tt[32][33];
        #pragma unroll
        for (int r = 0; r < 32; r += 8)
            tt[tr + r][tc] = jb.src[(size_t)(i0 + tr + r) * jb.ls + c0 + tc];
        __syncthreads();
        #pragma unroll
        for (int r = 0; r < 32; r += 8)
            jb.dst[(size_t)(c0 + tr + r) * jb.ld + i0 + tc] = f2bf(tt[tc][tr + r]);
    }
}

// ---------------- small fused kernels ----------------
__global__ __launch_bounds__(256) void k_head_s(const unsigned short* __restrict__ h2t,
    const float* __restrict__ w3t, const float* __restrict__ b3t,
    float* __restrict__ s)
{
    int t = threadIdx.x;
    int bl = t >> 3, k = t & 7;
    int b = blockIdx.x * 32 + bl;
    const unsigned short* ar = h2t + (size_t)b * H;
    float acc = b3t[k];
    for (int h0 = 0; h0 < H; h0 += 8) {
        short8v hv = *(const short8v*)(ar + h0);
        #pragma unroll
        for (int u = 0; u < 8; ++u)
            acc += bf2f((unsigned short)hv[u]) * w3t[(h0 + u) * K + k];
    }
    s[b * K + k] = acc;
}

__global__ __launch_bounds__(256) void k_q(const unsigned short* __restrict__ v0,
    const unsigned short* __restrict__ zb, float* __restrict__ q)
{
    int w = threadIdx.x >> 6, lane = threadIdx.x & 63;
    int idx = blockIdx.x * 4 + w;
    int b = idx >> 3, k = idx & 7;
    const unsigned short* vr = v0 + ((size_t)b * K + k) * N;
    const unsigned short* xr = zb + (size_t)b * 1024 + 512;
    short8v vv = *(const short8v*)(vr + lane * 8);
    short8v xv = *(const short8v*)(xr + lane * 8);
    float s = 0.f;
    #pragma unroll
    for (int t = 0; t < 8; ++t)
        s += bf2f((unsigned short)vv[t]) * bf2f((unsigned short)xv[t]);
    for (int off = 32; off; off >>= 1) s += __shfl_down(s, off, 64);
    if (lane == 0) q[idx] = s;
}

__global__ __launch_bounds__(256) void k_d(const float* __restrict__ s,
    const float* __restrict__ q, float* __restrict__ alpha,
    float* __restrict__ dd, int Bc)
{
    int b = blockIdx.x * 256 + threadIdx.x;
    if (b >= Bc) return;
    float sv[K], qv[K];
    float m = -1e30f;
    #pragma unroll
    for (int k = 0; k < K; ++k) { sv[k] = s[b * K + k]; m = fmaxf(m, sv[k]); }
    float sum = 0.f;
    #pragma unroll
    for (int k = 0; k < K; ++k) { sv[k] = expf(sv[k] - m); sum += sv[k]; }
    float inv = 1.f / sum, qbar = 0.f;
    #pragma unroll
    for (int k = 0; k < K; ++k) { sv[k] *= inv; qv[k] = q[b * K + k]; qbar += sv[k] * qv[k]; }
    #pragma unroll
    for (int k = 0; k < K; ++k) {
        alpha[b * K + k] = sv[k];
        dd[b * K + k] = sv[k] * (qv[k] - qbar);
    }
}

// merged u2 for all three subnets
__global__ __launch_bounds__(256) void k_u2(
    const unsigned short* __restrict__ d2_0, const unsigned short* __restrict__ d2_1,
    const unsigned short* __restrict__ d2_t,
    const float* __restrict__ w3_0, const float* __restrict__ w3_1,
    const float* __restrict__ w3t, const float* __restrict__ dd,
    unsigned short* __restrict__ u2_0, unsigned short* __restrict__ u2_1,
    unsigned short* __restrict__ u2_t)
{
    int g = blockIdx.x * 256 + threadIdx.x;
    int h = g & (H - 1), b = g >> 8;
    u2_0[g] = f2bf(w3_0[h] * bf2f(d2_0[g]));
    u2_1[g] = f2bf(w3_1[h] * bf2f(d2_1[g]));
    float s = 0.f;
    #pragma unroll
    for (int k = 0; k < K; ++k) s += w3t[h * K + k] * dd[b * K + k];
    u2_t[g] = f2bf(s * bf2f(d2_t[g]));
}

// fallback (chunked) path: out[:, :N] -= sum_k a_k v1; out[:, N:] -= sum_k a_k v0
__global__ __launch_bounds__(256) void k_gxq2(const unsigned short* __restrict__ v0,
    const unsigned short* __restrict__ v1, const float* __restrict__ alpha,
    float* __restrict__ out)
{
    int g = blockIdx.x * 256 + threadIdx.x;
    int b = g >> 6, jb = (g & 63) << 3;
    float al[K];
    #pragma unroll
    for (int k = 0; k < K; ++k) al[k] = alpha[b * K + k];
    const unsigned short* pv0 = v0 + (size_t)b * K * N + jb;
    const unsigned short* pv1 = v1 + (size_t)b * K * N + jb;
    float s0[8] = {}, s1[8] = {};
    #pragma unroll
    for (int k = 0; k < K; ++k) {
        short8v w1 = *(const short8v*)(pv1 + (size_t)k * N);
        short8v w0 = *(const short8v*)(pv0 + (size_t)k * N);
        #pragma unroll
        for (int t = 0; t < 8; ++t) {
            s0[t] += al[k] * bf2f((unsigned short)w1[t]);
            s1[t] += al[k] * bf2f((unsigned short)w0[t]);
        }
    }
    float* o0 = out + (size_t)b * 1024 + jb;
    float* o1 = o0 + 512;
    float4 x0 = *(float4*)o0, x1 = *(float4*)(o0 + 4);
    x0.x -= s0[0]; x0.y -= s0[1]; x0.z -= s0[2]; x0.w -= s0[3];
    x1.x -= s0[4]; x1.y -= s0[5]; x1.z -= s0[6]; x1.w -= s0[7];
    *(float4*)o0 = x0; *(float4*)(o0 + 4) = x1;
    float4 y0 = *(float4*)o1, y1 = *(float4*)(o1 + 4);
    y0.x -= s1[0]; y0.y -= s1[1]; y0.z -= s1[2]; y0.w -= s1[3];
    y1.x -= s1[4]; y1.y -= s1[5]; y1.z -= s1[6]; y1.w -= s1[7];
    *(float4*)o1 = y0; *(float4*)(o1 + 4) = y1;
}

extern "C" void kernel_launch(void* const* d_in, const int* in_sizes, int n_in,
                              void* d_out, int out_size, void* d_ws, size_t ws_size,
                              hipStream_t stream) {
    const float* z     = (const float*)d_in[0];
    const float* g0_w1 = (const float*)d_in[1];  const float* g0_b1 = (const float*)d_in[2];
    const float* g0_w2 = (const float*)d_in[3];  const float* g0_b2 = (const float*)d_in[4];
    const float* g0_w3 = (const float*)d_in[5];
    const float* g1_w1 = (const float*)d_in[7];  const float* g1_b1 = (const float*)d_in[8];
    const float* g1_w2 = (const float*)d_in[9];  const float* g1_b2 = (const float*)d_in[10];
    const float* g1_w3 = (const float*)d_in[11];
    const float* gt_w1 = (const float*)d_in[13]; const float* gt_b1 = (const float*)d_in[14];
    const float* gt_w2 = (const float*)d_in[15]; const float* gt_b2 = (const float*)d_in[16];
    const float* gt_w3 = (const float*)d_in[17]; const float* gt_b3 = (const float*)d_in[18];
    const float* W     = (const float*)d_in[19];
    float* out = (float*)d_out;

    // ---- workspace layout ----
    char* wsb = (char*)d_ws;
    size_t off = 0;
    auto aus = [&](size_t n) -> unsigned short* {
        unsigned short* r = (unsigned short*)(wsb + off);
        off += ((n * 2 + 255) & ~(size_t)255);
        return r;
    };
    auto af4 = [&](size_t n) -> float* {
        float* r = (float*)(wsb + off);
        off += ((n * 4 + 255) & ~(size_t)255);
        return r;
    };

    unsigned short* Zbf  = aus((size_t)BTOT * 1024);
    unsigned short* Wbf  = aus((size_t)K * N * N);
    unsigned short* WTbf = aus((size_t)K * N * N);
    unsigned short* w1T[3], *w2T[3], *w2N[3];
    for (int i = 0; i < 3; ++i) w1T[i] = aus((size_t)H * N);
    for (int i = 0; i < 3; ++i) w2T[i] = aus((size_t)H * H);
    for (int i = 0; i < 3; ++i) w2N[i] = aus((size_t)H * H);
    unsigned short* w1N1  = aus((size_t)N * H);
    unsigned short* w1cat = aus((size_t)N * 2 * H);
    unsigned short* h1[3], *d1b[3], *d2b[3], *u2[3];
    for (int i = 0; i < 3; ++i) h1[i]  = aus((size_t)BTOT * H);
    for (int i = 0; i < 3; ++i) d1b[i] = aus((size_t)BTOT * H);
    for (int i = 0; i < 3; ++i) d2b[i] = aus((size_t)BTOT * H);
    for (int i = 0; i < 3; ++i) u2[i]  = aus((size_t)BTOT * H);
    unsigned short* h2t   = aus((size_t)BTOT * H);
    unsigned short* t2cat = aus((size_t)BTOT * 512);
    unsigned short* t21   = aus((size_t)BTOT * H);
    float* sbuf = af4((size_t)BTOT * K);
    float* qbuf = af4((size_t)BTOT * K);
    float* abuf = af4((size_t)BTOT * K);
    float* dbuf = af4((size_t)BTOT * K);

    int Bcv = BTOT;
    while (off + 2 * (((size_t)Bcv * K * N * 2 + 255) & ~(size_t)255) > ws_size && Bcv > 128)
        Bcv >>= 1;
    unsigned short* v0 = aus((size_t)Bcv * K * N);
    unsigned short* v1 = aus((size_t)Bcv * K * N);
    const bool full = (Bcv == BTOT);

    const dim3 blk(256);

    if (!full)  // fallback path needs zeroed out for RMW accumulation
        hipMemsetAsync(d_out, 0, (size_t)out_size * sizeof(float), stream);

    // ---- prep: bf16 copies ----
    k_cvt_z<<<BTOT * 1024 / (256 * 4), blk, 0, stream>>>(z, Zbf);
    k_transpose_w<<<dim3(N / 32, N / 32, K), blk, 0, stream>>>(W, Wbf, WTbf);

    CvtTable T;
    int nj = 0, tot = 0;
    auto addjob = [&](const float* src, int ls, unsigned short* dst, int ld,
                      int rows, int cols, int trans) {
        CvtJob jb; jb.src = src; jb.dst = dst; jb.ls = ls; jb.ld = ld;
        jb.cols32 = cols / 32; jb.tiles = (rows / 32) * (cols / 32); jb.trans = trans;
        T.j[nj++] = jb; tot += jb.tiles;
    };
    addjob(g0_w1, H, w1T[0], N, N, H, 1);
    addjob(g1_w1, H, w1T[1], N, N, H, 1);
    addjob(gt_w1, H, w1T[2], N, N, H, 1);
    addjob(g0_w2, H, w2T[0], H, H, H, 1);
    addjob(g1_w2, H, w2T[1], H, H, H, 1);
    addjob(gt_w2, H, w2T[2], H, H, H, 1);
    addjob(g0_w2, H, w2N[0], H, H, H, 0);
    addjob(g1_w2, H, w2N[1], H, H, H, 0);
    addjob(gt_w2, H, w2N[2], H, H, H, 0);
    addjob(g1_w1, H, w1N1, H, N, H, 0);
    addjob(g0_w1, H, w1cat, 2 * H, N, H, 0);
    addjob(gt_w1, H, w1cat + H, 2 * H, N, H, 0);
    k_cvt_w<<<tot, blk, 0, stream>>>(T);

    auto mk = [](const unsigned short* A, int lda, const unsigned short* Bt, int ldbt, int Ka) {
        GArg g; g.A = A; g.Bt = Bt; g.bias = nullptr; g.dmul = nullptr;
        g.alpha = nullptr; g.vsub = nullptr;
        g.ob = nullptr; g.ob2 = nullptr; g.of = nullptr;
        g.lda = lda; g.ldbt = ldbt; g.Ka = Ka; g.lddm = 0; g.ldob = 0; g.ldof = 0;
        return g;
    };

    // ---- forward L1 (grouped) -> h1 (silu) + d1 (dsilu) ----
    {
        const float* bs[3] = {g0_b1, g1_b1, gt_b1};
        GArg a[3];
        for (int i = 0; i < 3; ++i) {
            a[i] = mk(Zbf + (i == 1 ? 512 : 0), 1024, w1T[i], N, N);
            a[i].bias = bs[i]; a[i].ob = h1[i]; a[i].ob2 = d1b[i]; a[i].ldob = H;
        }
        gemm_g<EPI_FWD><<<dim3(H / 128, BTOT / 128, 3), blk, 0, stream>>>(a[0], a[1], a[2]);
    }
    // ---- forward L2 (grouped) -> d2 (dsilu); h2 only for gate net ----
    {
        const float* bs[3] = {g0_b2, g1_b2, gt_b2};
        GArg a[3];
        for (int i = 0; i < 3; ++i) {
            a[i] = mk(h1[i], H, w2T[i], H, H);
            a[i].bias = bs[i]; a[i].ob = (i == 2) ? h2t : nullptr;
            a[i].ob2 = d2b[i]; a[i].ldob = H;
        }
        gemm_g<EPI_FWD><<<dim3(H / 128, BTOT / 128, 3), blk, 0, stream>>>(a[0], a[1], a[2]);
    }
    k_head_s<<<BTOT / 32, blk, 0, stream>>>(h2t, gt_w3, gt_b3, sbuf);

    // ---- bilinear path ----
    for (int cb = 0; cb < BTOT; cb += Bcv) {
        GArg a[2];
        a[0] = mk(Zbf + (size_t)cb * 1024, 1024, Wbf, N, N);
        a[0].ob = v0; a[0].ldob = K * N;
        a[1] = mk(Zbf + (size_t)cb * 1024 + 512, 1024, WTbf, N, N);
        a[1].ob = v1; a[1].ldob = K * N;
        gemm_g<EPI_BF><<<dim3(K * N / 128, Bcv / 128, 2), blk, 0, stream>>>(a[0], a[1], a[1]);

        k_q<<<Bcv * K / 4, blk, 0, stream>>>(v0, Zbf + (size_t)cb * 1024, qbuf + (size_t)cb * K);
        k_d<<<(Bcv + 255) / 256, blk, 0, stream>>>(sbuf + (size_t)cb * K, qbuf + (size_t)cb * K,
                                                   abuf + (size_t)cb * K, dbuf + (size_t)cb * K, Bcv);
        if (!full)
            k_gxq2<<<Bcv * 64 / 256, blk, 0, stream>>>(v0, v1, abuf + (size_t)cb * K,
                                                       out + (size_t)cb * 1024);
    }

    // ---- backward: u2 = dL/da2 (all three subnets, one launch) ----
    k_u2<<<BTOT * H / 256, blk, 0, stream>>>(d2b[0], d2b[1], d2b[2],
                                             g0_w3, g1_w3, gt_w3, dbuf,
                                             u2[0], u2[1], u2[2]);

    // ---- backward L2 (grouped): t2 = (u2 @ w2^T) * d1 -> bf16 ----
    {
        GArg a[3];
        a[0] = mk(u2[0], H, w2N[0], H, H);
        a[0].dmul = d1b[0]; a[0].lddm = H; a[0].ob = t2cat;     a[0].ldob = 512;
        a[1] = mk(u2[1], H, w2N[1], H, H);
        a[1].dmul = d1b[1]; a[1].lddm = H; a[1].ob = t21;       a[1].ldob = H;
        a[2] = mk(u2[2], H, w2N[2], H, H);
        a[2].dmul = d1b[2]; a[2].lddm = H; a[2].ob = t2cat + H; a[2].ldob = 512;
        gemm_g<EPI_BWD2><<<dim3(H / 128, BTOT / 128, 3), blk, 0, stream>>>(a[0], a[1], a[2]);
    }
    // ---- backward L1 (grouped): g0+gt concatenated (Ka=512), g1 ----
    // full path: epilogue fuses  out = -acc - sum_k alpha_k * v  (kills k_gxq2)
    {
        GArg a[2];
        a[0] = mk(t2cat, 512, w1cat, 2 * H, 512);
        a[0].of = out;       a[0].ldof = 1024;
        a[1] = mk(t21, H, w1N1, H, H);
        a[1].of = out + 512; a[1].ldof = 1024;
        if (full) {
            a[0].alpha = abuf; a[0].vsub = v1;
            a[1].alpha = abuf; a[1].vsub = v0;
            gemm_g<EPI_NEGV><<<dim3(N / 128, BTOT / 128, 2), blk, 0, stream>>>(a[0], a[1], a[1]);
        } else {
            gemm_g<EPI_NEG><<<dim3(N / 128, BTOT / 128, 2), blk, 0, stream>>>(a[0], a[1], a[1]);
        }
    }
}